// Round 1
// baseline (114.732 us; speedup 1.0000x reference)
//
#include <hip/hip_runtime.h>

#define H_ 16
#define S_ 4096
#define D_ 64
#define BS_ 64
#define NB_ 64            // S_/BS_
#define NUNITS (H_*NB_)   // 1024
#define SCALE_ 0.125f     // 1/sqrt(64)
#define NSLICE 16
#define ROWS_PER_SLICE (S_/NSLICE)  // 256

// d_ws layout:
//   [0, H_*NSLICE*D_)            float partial sums  (16*16*64 = 16384 floats)
//   [H_*NSLICE*D_, +H_*D_)       float vtot[H_][D_]

__global__ __launch_bounds__(256) void vsum_part(const float* __restrict__ V,
                                                 float* __restrict__ part) {
    const int blk = blockIdx.x;            // h*NSLICE + slice
    const int h = blk >> 4, sl = blk & 15;
    const int t = threadIdx.x;
    const int d4 = t & 15, rg = t >> 4;
    const float4* vp = (const float4*)(V + ((size_t)h * S_ + (size_t)sl * ROWS_PER_SLICE) * D_);
    float4 acc = make_float4(0.f, 0.f, 0.f, 0.f);
    for (int s = rg; s < ROWS_PER_SLICE; s += 16) {
        float4 v = vp[s * 16 + d4];
        acc.x += v.x; acc.y += v.y; acc.z += v.z; acc.w += v.w;
    }
    __shared__ float4 red[16][16];
    red[rg][d4] = acc;
    __syncthreads();
    if (rg == 0) {
        float4 s0 = red[0][d4];
        #pragma unroll
        for (int r = 1; r < 16; ++r) {
            float4 v = red[r][d4];
            s0.x += v.x; s0.y += v.y; s0.z += v.z; s0.w += v.w;
        }
        ((float4*)(part + (size_t)blk * D_))[d4] = s0;
    }
}

__global__ __launch_bounds__(64) void vsum_final(const float* __restrict__ part,
                                                 float* __restrict__ vtot) {
    const int h = blockIdx.x;
    const int d = threadIdx.x;
    float s = 0.f;
    #pragma unroll
    for (int sl = 0; sl < NSLICE; ++sl) s += part[(h * NSLICE + sl) * D_ + d];
    vtot[h * D_ + d] = s;
}

__global__ __launch_bounds__(256) void battn(const float* __restrict__ Q,
                                             const float* __restrict__ K,
                                             const float* __restrict__ V,
                                             const float* __restrict__ vtot,
                                             float* __restrict__ O) {
    const int unit = blockIdx.x;
    const int h = unit >> 6, b = unit & 63;
    const int t = threadIdx.x;
    const int tx = t & 15, ty = t >> 4;

    __shared__ float Qs[64][65];   // aliased as P after QK^T
    __shared__ float Ks[64][65];
    __shared__ float Vs[64][65];

    const size_t base = ((size_t)h * S_ + (size_t)b * BS_) * D_;
    const float4* q4 = (const float4*)(Q + base);
    const float4* k4 = (const float4*)(K + base);
    const float4* v4 = (const float4*)(V + base);

    // cooperative tile load: 1024 float4 per tile, 4 per thread
    #pragma unroll
    for (int it = 0; it < 4; ++it) {
        int idx = t + it * 256;
        int r = idx >> 4, c = (idx & 15) << 2;
        float4 qv = q4[idx];
        float4 kv = k4[idx];
        float4 vv = v4[idx];
        Qs[r][c] = qv.x; Qs[r][c + 1] = qv.y; Qs[r][c + 2] = qv.z; Qs[r][c + 3] = qv.w;
        Ks[r][c] = kv.x; Ks[r][c + 1] = kv.y; Ks[r][c + 2] = kv.z; Ks[r][c + 3] = kv.w;
        Vs[r][c] = vv.x; Vs[r][c + 1] = vv.y; Vs[r][c + 2] = vv.z; Vs[r][c + 3] = vv.w;
    }
    __syncthreads();

    // QK^T: rows q = ty + 16i, cols k = tx + 16j (strided 4x4 register tile)
    float s[4][4];
    #pragma unroll
    for (int i = 0; i < 4; ++i)
        #pragma unroll
        for (int j = 0; j < 4; ++j) s[i][j] = 0.f;

    #pragma unroll 4
    for (int d = 0; d < 64; ++d) {
        float qv[4], kv[4];
        #pragma unroll
        for (int i = 0; i < 4; ++i) qv[i] = Qs[ty + 16 * i][d];
        #pragma unroll
        for (int j = 0; j < 4; ++j) kv[j] = Ks[tx + 16 * j][d];
        #pragma unroll
        for (int i = 0; i < 4; ++i)
            #pragma unroll
            for (int j = 0; j < 4; ++j) s[i][j] = fmaf(qv[i], kv[j], s[i][j]);
    }

    #pragma unroll
    for (int i = 0; i < 4; ++i)
        #pragma unroll
        for (int j = 0; j < 4; ++j) s[i][j] *= SCALE_;

    // per-row (q = ty + 16i) softmax stats across the 16 tx lanes
    float em[4], inv[4];
    #pragma unroll
    for (int i = 0; i < 4; ++i) {
        float mx = fmaxf(fmaxf(s[i][0], s[i][1]), fmaxf(s[i][2], s[i][3]));
        #pragma unroll
        for (int off = 1; off < 16; off <<= 1) mx = fmaxf(mx, __shfl_xor(mx, off, 16));
        mx = fmaxf(mx, 0.f);                 // off-block entries contribute score 0
        em[i] = __expf(-mx);
        float zs = 0.f;
        #pragma unroll
        for (int j = 0; j < 4; ++j) {
            s[i][j] = __expf(s[i][j] - mx) - em[i];   // p_k = e^{s-m} - e^{-m}
            zs += s[i][j];
        }
        #pragma unroll
        for (int off = 1; off < 16; off <<= 1) zs += __shfl_xor(zs, off, 16);
        inv[i] = 1.0f / (zs + (float)S_ * em[i]);     // Z = sum_p + S*e^{-m}
    }

    __syncthreads();   // all Q reads done; safe to overwrite Qs with P
    #pragma unroll
    for (int i = 0; i < 4; ++i)
        #pragma unroll
        for (int j = 0; j < 4; ++j)
            Qs[ty + 16 * i][tx + 16 * j] = s[i][j] * inv[i];
    __syncthreads();

    // PV: O[q][d] = sum_k P[q][k] * V[k][d], d = tx + 16j
    float o[4][4];
    #pragma unroll
    for (int i = 0; i < 4; ++i)
        #pragma unroll
        for (int j = 0; j < 4; ++j) o[i][j] = 0.f;

    #pragma unroll 4
    for (int k = 0; k < 64; ++k) {
        float pv[4], vv[4];
        #pragma unroll
        for (int i = 0; i < 4; ++i) pv[i] = Qs[ty + 16 * i][k];
        #pragma unroll
        for (int j = 0; j < 4; ++j) vv[j] = Vs[k][tx + 16 * j];
        #pragma unroll
        for (int i = 0; i < 4; ++i)
            #pragma unroll
            for (int j = 0; j < 4; ++j) o[i][j] = fmaf(pv[i], vv[j], o[i][j]);
    }

    const float* vt = vtot + h * D_;
    float vtd[4];
    #pragma unroll
    for (int j = 0; j < 4; ++j) vtd[j] = vt[tx + 16 * j];

    float* op = O + base;
    #pragma unroll
    for (int i = 0; i < 4; ++i) {
        float c = em[i] * inv[i];
        #pragma unroll
        for (int j = 0; j < 4; ++j)
            op[(ty + 16 * i) * D_ + tx + 16 * j] = o[i][j] + c * vtd[j];
    }
}

extern "C" void kernel_launch(void* const* d_in, const int* in_sizes, int n_in,
                              void* d_out, int out_size, void* d_ws, size_t ws_size,
                              hipStream_t stream) {
    const float* Q = (const float*)d_in[0];
    const float* K = (const float*)d_in[1];
    const float* V = (const float*)d_in[2];
    float* out = (float*)d_out;
    float* part = (float*)d_ws;
    float* vtot = part + (size_t)H_ * NSLICE * D_;

    vsum_part<<<H_ * NSLICE, 256, 0, stream>>>(V, part);
    vsum_final<<<H_, 64, 0, stream>>>(part, vtot);
    battn<<<NUNITS, 256, 0, stream>>>(Q, K, V, vtot, out);
}

// Round 4
// 103.491 us; speedup vs baseline: 1.1086x; 1.1086x over previous
//
#include <hip/hip_runtime.h>

#define H_ 16
#define S_ 4096
#define D_ 64
#define NB_ 64            // S_/64
#define NUNITS (H_*NB_)   // 1024
#define NSLICE 16
#define ROWS_PER_SLICE (S_/NSLICE)  // 256

typedef __bf16 bf16x8 __attribute__((ext_vector_type(8)));
typedef float f32x4 __attribute__((ext_vector_type(4)));

static __device__ __forceinline__ f32x4 mfma16(bf16x8 a, bf16x8 b, f32x4 c) {
    return __builtin_amdgcn_mfma_f32_16x16x32_bf16(a, b, c, 0, 0, 0);
}

#define SPLIT1(x, hv, lv, idx) { float _x = (x); __bf16 _h = (__bf16)_x; (hv)[idx] = _h; (lv)[idx] = (__bf16)(_x - (float)_h); }

static __device__ __forceinline__ void split8(float4 a, float4 b, bf16x8& hi, bf16x8& lo) {
    SPLIT1(a.x, hi, lo, 0) SPLIT1(a.y, hi, lo, 1) SPLIT1(a.z, hi, lo, 2) SPLIT1(a.w, hi, lo, 3)
    SPLIT1(b.x, hi, lo, 4) SPLIT1(b.y, hi, lo, 5) SPLIT1(b.z, hi, lo, 6) SPLIT1(b.w, hi, lo, 7)
}

// ---------------- V row-sum (two-stage, deterministic) ----------------
__global__ __launch_bounds__(256) void vsum_part(const float* __restrict__ V,
                                                 float* __restrict__ part) {
    const int blk = blockIdx.x;            // h*NSLICE + slice
    const int h = blk >> 4, sl = blk & 15;
    const int t = threadIdx.x;
    const int d4 = t & 15, rg = t >> 4;
    const float4* vp = (const float4*)(V + ((size_t)h * S_ + (size_t)sl * ROWS_PER_SLICE) * D_);
    float4 acc = make_float4(0.f, 0.f, 0.f, 0.f);
    for (int s = rg; s < ROWS_PER_SLICE; s += 16) {
        float4 v = vp[s * 16 + d4];
        acc.x += v.x; acc.y += v.y; acc.z += v.z; acc.w += v.w;
    }
    __shared__ float4 red[16][16];
    red[rg][d4] = acc;
    __syncthreads();
    if (rg == 0) {
        float4 s0 = red[0][d4];
        #pragma unroll
        for (int r = 1; r < 16; ++r) {
            float4 v = red[r][d4];
            s0.x += v.x; s0.y += v.y; s0.z += v.z; s0.w += v.w;
        }
        ((float4*)(part + (size_t)blk * D_))[d4] = s0;
    }
}

__global__ __launch_bounds__(64) void vsum_final(const float* __restrict__ part,
                                                 float* __restrict__ vtot) {
    const int h = blockIdx.x;
    const int d = threadIdx.x;
    float s = 0.f;
    #pragma unroll
    for (int sl = 0; sl < NSLICE; ++sl) s += part[(h * NSLICE + sl) * D_ + d];
    vtot[h * D_ + d] = s;
}

// ---------------- block attention: MFMA bf16x2 (hi/lo split) ----------------
__global__ __launch_bounds__(256, 3) void battn(const float* __restrict__ Q,
                                                const float* __restrict__ K,
                                                const float* __restrict__ V,
                                                const float* __restrict__ vtot,
                                                float* __restrict__ O) {
    const int unit = blockIdx.x;
    const int h = unit >> 6, b = unit & 63;
    const int t = threadIdx.x;
    const int w = t >> 6;          // wave 0..3, owns rows [w*16, w*16+16)
    const int lane = t & 63;
    const int lr = lane & 15;      // row/col within 16-tile
    const int lg = lane >> 4;      // k-group 0..3

    // V transposed (col-major) + P, both as bf16 hi/lo. stride 72 -> 16B-aligned rows
    __shared__ __bf16 VtH[64][72];
    __shared__ __bf16 VtL[64][72];
    __shared__ __bf16 PH[64][72];
    __shared__ __bf16 PL[64][72];

    const size_t base = ((size_t)h * S_ + (size_t)b * 64) * D_;

    // ---- stage V transposed as bf16 hi/lo (cooperative, coalesced float4 reads) ----
    const float4* v4 = (const float4*)(V + base);
    #pragma unroll
    for (int it = 0; it < 4; ++it) {
        int idx = t + it * 256;        // 0..1023
        int k  = idx >> 4;             // V row (seq pos in block)
        int n0 = (idx & 15) << 2;      // V col base
        float4 vv = v4[idx];
        { float x = vv.x; __bf16 hh = (__bf16)x; VtH[n0+0][k] = hh; VtL[n0+0][k] = (__bf16)(x - (float)hh); }
        { float x = vv.y; __bf16 hh = (__bf16)x; VtH[n0+1][k] = hh; VtL[n0+1][k] = (__bf16)(x - (float)hh); }
        { float x = vv.z; __bf16 hh = (__bf16)x; VtH[n0+2][k] = hh; VtL[n0+2][k] = (__bf16)(x - (float)hh); }
        { float x = vv.w; __bf16 hh = (__bf16)x; VtH[n0+3][k] = hh; VtL[n0+3][k] = (__bf16)(x - (float)hh); }
    }

    // ---- Q fragments (pre-scaled by 1/8; exact pow2, no extra rounding) ----
    bf16x8 qh[2], ql[2];
    {
        const float* qrow = Q + base + (size_t)(w * 16 + lr) * D_;
        #pragma unroll
        for (int kk = 0; kk < 2; ++kk) {
            const float4* p = (const float4*)(qrow + kk * 32 + lg * 8);
            float4 a = p[0], c2 = p[1];
            a.x *= 0.125f; a.y *= 0.125f; a.z *= 0.125f; a.w *= 0.125f;
            c2.x *= 0.125f; c2.y *= 0.125f; c2.z *= 0.125f; c2.w *= 0.125f;
            split8(a, c2, qh[kk], ql[kk]);
        }
    }

    // ---- S = (Q/8) K^T via 3-term split MFMA ----
    f32x4 acc[4];
    #pragma unroll
    for (int j = 0; j < 4; ++j) acc[j] = f32x4{0.f, 0.f, 0.f, 0.f};

    #pragma unroll
    for (int j = 0; j < 4; ++j) {      // K col-tile
        const float* krow = K + base + (size_t)(j * 16 + lr) * D_;
        #pragma unroll
        for (int kk = 0; kk < 2; ++kk) {
            const float4* p = (const float4*)(krow + kk * 32 + lg * 8);
            bf16x8 kh, kl;
            split8(p[0], p[1], kh, kl);
            acc[j] = mfma16(qh[kk], kh, acc[j]);
            acc[j] = mfma16(ql[kk], kh, acc[j]);
            acc[j] = mfma16(qh[kk], kl, acc[j]);
        }
    }

    // ---- softmax (row = w*16 + lg*4 + r, cols spread over 16 lanes x 4 tiles) ----
    float em[4], inv[4];
    #pragma unroll
    for (int r = 0; r < 4; ++r) {
        float mx = fmaxf(fmaxf(acc[0][r], acc[1][r]), fmaxf(acc[2][r], acc[3][r]));
        #pragma unroll
        for (int off = 1; off < 16; off <<= 1) mx = fmaxf(mx, __shfl_xor(mx, off, 16));
        mx = fmaxf(mx, 0.f);           // off-block entries have score 0
        float e = __expf(-mx);
        float p0 = __expf(acc[0][r] - mx) - e;
        float p1 = __expf(acc[1][r] - mx) - e;
        float p2 = __expf(acc[2][r] - mx) - e;
        float p3 = __expf(acc[3][r] - mx) - e;
        float zs = p0 + p1 + p2 + p3;
        #pragma unroll
        for (int off = 1; off < 16; off <<= 1) zs += __shfl_xor(zs, off, 16);
        float iv = 1.0f / (zs + 4096.0f * e);   // Z = sum_p + S*e^{-m}
        em[r] = e; inv[r] = iv;
        int row = w * 16 + lg * 4 + r;
        { float pn = p0 * iv; __bf16 hh = (__bf16)pn; PH[row][lr +  0] = hh; PL[row][lr +  0] = (__bf16)(pn - (float)hh); }
        { float pn = p1 * iv; __bf16 hh = (__bf16)pn; PH[row][lr + 16] = hh; PL[row][lr + 16] = (__bf16)(pn - (float)hh); }
        { float pn = p2 * iv; __bf16 hh = (__bf16)pn; PH[row][lr + 32] = hh; PL[row][lr + 32] = (__bf16)(pn - (float)hh); }
        { float pn = p3 * iv; __bf16 hh = (__bf16)pn; PH[row][lr + 48] = hh; PL[row][lr + 48] = (__bf16)(pn - (float)hh); }
    }

    __syncthreads();   // V staging visibility across waves (P is intra-wave only)

    // ---- O = P V via 3-term split MFMA ----
    bf16x8 pfh[2], pfl[2];
    {
        const int prow = w * 16 + lr;
        #pragma unroll
        for (int kk = 0; kk < 2; ++kk) {
            pfh[kk] = *(const bf16x8*)&PH[prow][kk * 32 + lg * 8];
            pfl[kk] = *(const bf16x8*)&PL[prow][kk * 32 + lg * 8];
        }
    }

    f32x4 oacc[4];
    #pragma unroll
    for (int j = 0; j < 4; ++j) oacc[j] = f32x4{0.f, 0.f, 0.f, 0.f};

    #pragma unroll
    for (int j = 0; j < 4; ++j) {      // output col-tile
        #pragma unroll
        for (int kk = 0; kk < 2; ++kk) {
            bf16x8 vh = *(const bf16x8*)&VtH[lr + 16 * j][kk * 32 + lg * 8];
            bf16x8 vl = *(const bf16x8*)&VtL[lr + 16 * j][kk * 32 + lg * 8];
            oacc[j] = mfma16(pfh[kk], vh, oacc[j]);
            oacc[j] = mfma16(pfl[kk], vh, oacc[j]);
            oacc[j] = mfma16(pfh[kk], vl, oacc[j]);
        }
    }

    // ---- epilogue: add off-block correction em/Z * vtot, store ----
    const float* vt = vtot + h * D_;
    float* op = O + base + (size_t)(w * 16) * D_;
    #pragma unroll
    for (int r = 0; r < 4; ++r) {
        float c = em[r] * inv[r];
        int row = lg * 4 + r;
        #pragma unroll
        for (int j = 0; j < 4; ++j) {
            int col = lr + 16 * j;
            op[row * D_ + col] = oacc[j][r] + c * vt[col];
        }
    }
}

extern "C" void kernel_launch(void* const* d_in, const int* in_sizes, int n_in,
                              void* d_out, int out_size, void* d_ws, size_t ws_size,
                              hipStream_t stream) {
    const float* Q = (const float*)d_in[0];
    const float* K = (const float*)d_in[1];
    const float* V = (const float*)d_in[2];
    float* out = (float*)d_out;
    float* part = (float*)d_ws;
    float* vtot = part + (size_t)H_ * NSLICE * D_;

    vsum_part<<<H_ * NSLICE, 256, 0, stream>>>(V, part);
    vsum_final<<<H_, 64, 0, stream>>>(part, vtot);
    battn<<<NUNITS, 256, 0, stream>>>(Q, K, V, vtot, out);
}

// Round 5
// 101.021 us; speedup vs baseline: 1.1357x; 1.0244x over previous
//
#include <hip/hip_runtime.h>

#define H_ 16
#define S_ 4096
#define D_ 64
#define NB_ 64            // S_/64
#define NUNITS (H_*NB_)   // 1024
#define NSLICE 32
#define ROWS_PER_SLICE (S_/NSLICE)  // 128

typedef __bf16 bf16x8 __attribute__((ext_vector_type(8)));
typedef float f32x4 __attribute__((ext_vector_type(4)));

static __device__ __forceinline__ f32x4 mfma16(bf16x8 a, bf16x8 b, f32x4 c) {
    return __builtin_amdgcn_mfma_f32_16x16x32_bf16(a, b, c, 0, 0, 0);
}

#define SPLIT1(x, hv, lv, idx) { float _x = (x); __bf16 _h = (__bf16)_x; (hv)[idx] = _h; (lv)[idx] = (__bf16)(_x - (float)_h); }

static __device__ __forceinline__ void split8(float4 a, float4 b, bf16x8& hi, bf16x8& lo) {
    SPLIT1(a.x, hi, lo, 0) SPLIT1(a.y, hi, lo, 1) SPLIT1(a.z, hi, lo, 2) SPLIT1(a.w, hi, lo, 3)
    SPLIT1(b.x, hi, lo, 4) SPLIT1(b.y, hi, lo, 5) SPLIT1(b.z, hi, lo, 6) SPLIT1(b.w, hi, lo, 7)
}

// ---------------- V partial row-sums: part[h][sl][d] = sum over 128 rows ----------------
__global__ __launch_bounds__(256) void vsum_part(const float* __restrict__ V,
                                                 float* __restrict__ part) {
    const int blk = blockIdx.x;            // h*NSLICE + slice
    const int h = blk >> 5, sl = blk & 31;
    const int t = threadIdx.x;
    const int d4 = t & 15, rg = t >> 4;
    const float4* vp = (const float4*)(V + ((size_t)h * S_ + (size_t)sl * ROWS_PER_SLICE) * D_);
    float4 acc = make_float4(0.f, 0.f, 0.f, 0.f);
    #pragma unroll
    for (int s = 0; s < ROWS_PER_SLICE / 16; ++s) {
        float4 v = vp[(rg + s * 16) * 16 + d4];
        acc.x += v.x; acc.y += v.y; acc.z += v.z; acc.w += v.w;
    }
    __shared__ float4 red[16][16];
    red[rg][d4] = acc;
    __syncthreads();
    if (rg == 0) {
        float4 s0 = red[0][d4];
        #pragma unroll
        for (int r = 1; r < 16; ++r) {
            float4 v = red[r][d4];
            s0.x += v.x; s0.y += v.y; s0.z += v.z; s0.w += v.w;
        }
        ((float4*)(part + (size_t)blk * D_))[d4] = s0;
    }
}

// ---------------- block attention: MFMA bf16 hi/lo split; vtot folded in ----------------
__global__ __launch_bounds__(256, 4) void battn(const float* __restrict__ Q,
                                                const float* __restrict__ K,
                                                const float* __restrict__ V,
                                                const float* __restrict__ part,
                                                float* __restrict__ O) {
    const int unit = blockIdx.x;
    const int h = unit >> 6, b = unit & 63;
    const int t = threadIdx.x;
    const int w = t >> 6;          // wave 0..3, owns rows [w*16, w*16+16)
    const int lane = t & 63;
    const int lr = lane & 15;      // row/col within 16-tile
    const int lg = lane >> 4;      // k-group 0..3

    // V transposed (col-major) + P, both as bf16 hi/lo. stride 72 -> 16B-aligned rows
    __shared__ __bf16 VtH[64][72];
    __shared__ __bf16 VtL[64][72];
    __shared__ __bf16 PH[64][72];
    __shared__ __bf16 PL[64][72];
    __shared__ float vt_lds[64];

    const size_t base = ((size_t)h * S_ + (size_t)b * 64) * D_;

    // ---- wave 0: reduce per-head V partials into vt_lds (visible after the barrier) ----
    if (t < 64) {
        const float* ph = part + (size_t)h * NSLICE * D_;
        float s = 0.f;
        #pragma unroll
        for (int sl = 0; sl < NSLICE; ++sl) s += ph[sl * D_ + t];
        vt_lds[t] = s;
    }

    // ---- stage V transposed as bf16 hi/lo (cooperative, coalesced float4 reads) ----
    const float4* v4 = (const float4*)(V + base);
    #pragma unroll
    for (int it = 0; it < 4; ++it) {
        int idx = t + it * 256;        // 0..1023
        int k  = idx >> 4;             // V row (seq pos in block)
        int n0 = (idx & 15) << 2;      // V col base
        float4 vv = v4[idx];
        { float x = vv.x; __bf16 hh = (__bf16)x; VtH[n0+0][k] = hh; VtL[n0+0][k] = (__bf16)(x - (float)hh); }
        { float x = vv.y; __bf16 hh = (__bf16)x; VtH[n0+1][k] = hh; VtL[n0+1][k] = (__bf16)(x - (float)hh); }
        { float x = vv.z; __bf16 hh = (__bf16)x; VtH[n0+2][k] = hh; VtL[n0+2][k] = (__bf16)(x - (float)hh); }
        { float x = vv.w; __bf16 hh = (__bf16)x; VtH[n0+3][k] = hh; VtL[n0+3][k] = (__bf16)(x - (float)hh); }
    }

    // ---- Q fragments (pre-scaled by 1/8; exact pow2, no extra rounding) ----
    bf16x8 qh[2], ql[2];
    {
        const float* qrow = Q + base + (size_t)(w * 16 + lr) * D_;
        #pragma unroll
        for (int kk = 0; kk < 2; ++kk) {
            const float4* p = (const float4*)(qrow + kk * 32 + lg * 8);
            float4 a = p[0], c2 = p[1];
            a.x *= 0.125f; a.y *= 0.125f; a.z *= 0.125f; a.w *= 0.125f;
            c2.x *= 0.125f; c2.y *= 0.125f; c2.z *= 0.125f; c2.w *= 0.125f;
            split8(a, c2, qh[kk], ql[kk]);
        }
    }

    // ---- S = (Q/8) K^T via 3-term split MFMA ----
    f32x4 acc[4];
    #pragma unroll
    for (int j = 0; j < 4; ++j) acc[j] = f32x4{0.f, 0.f, 0.f, 0.f};

    #pragma unroll
    for (int j = 0; j < 4; ++j) {      // K col-tile
        const float* krow = K + base + (size_t)(j * 16 + lr) * D_;
        #pragma unroll
        for (int kk = 0; kk < 2; ++kk) {
            const float4* p = (const float4*)(krow + kk * 32 + lg * 8);
            bf16x8 kh, kl;
            split8(p[0], p[1], kh, kl);
            acc[j] = mfma16(qh[kk], kh, acc[j]);
            acc[j] = mfma16(ql[kk], kh, acc[j]);
            acc[j] = mfma16(qh[kk], kl, acc[j]);
        }
    }

    // ---- softmax (row = w*16 + lg*4 + r, cols spread over 16 lanes x 4 tiles) ----
    float em[4], inv[4];
    #pragma unroll
    for (int r = 0; r < 4; ++r) {
        float mx = fmaxf(fmaxf(acc[0][r], acc[1][r]), fmaxf(acc[2][r], acc[3][r]));
        #pragma unroll
        for (int off = 1; off < 16; off <<= 1) mx = fmaxf(mx, __shfl_xor(mx, off, 16));
        mx = fmaxf(mx, 0.f);           // off-block entries have score 0
        float e = __expf(-mx);
        float p0 = __expf(acc[0][r] - mx) - e;
        float p1 = __expf(acc[1][r] - mx) - e;
        float p2 = __expf(acc[2][r] - mx) - e;
        float p3 = __expf(acc[3][r] - mx) - e;
        float zs = p0 + p1 + p2 + p3;
        #pragma unroll
        for (int off = 1; off < 16; off <<= 1) zs += __shfl_xor(zs, off, 16);
        float iv = 1.0f / (zs + 4096.0f * e);   // Z = sum_p + S*e^{-m}
        em[r] = e; inv[r] = iv;
        int row = w * 16 + lg * 4 + r;
        { float pn = p0 * iv; __bf16 hh = (__bf16)pn; PH[row][lr +  0] = hh; PL[row][lr +  0] = (__bf16)(pn - (float)hh); }
        { float pn = p1 * iv; __bf16 hh = (__bf16)pn; PH[row][lr + 16] = hh; PL[row][lr + 16] = (__bf16)(pn - (float)hh); }
        { float pn = p2 * iv; __bf16 hh = (__bf16)pn; PH[row][lr + 32] = hh; PL[row][lr + 32] = (__bf16)(pn - (float)hh); }
        { float pn = p3 * iv; __bf16 hh = (__bf16)pn; PH[row][lr + 48] = hh; PL[row][lr + 48] = (__bf16)(pn - (float)hh); }
    }

    __syncthreads();   // V staging + vt_lds visibility across waves (P is intra-wave only)

    // ---- O = P V via 3-term split MFMA ----
    bf16x8 pfh[2], pfl[2];
    {
        const int prow = w * 16 + lr;
        #pragma unroll
        for (int kk = 0; kk < 2; ++kk) {
            pfh[kk] = *(const bf16x8*)&PH[prow][kk * 32 + lg * 8];
            pfl[kk] = *(const bf16x8*)&PL[prow][kk * 32 + lg * 8];
        }
    }

    f32x4 oacc[4];
    #pragma unroll
    for (int j = 0; j < 4; ++j) oacc[j] = f32x4{0.f, 0.f, 0.f, 0.f};

    #pragma unroll
    for (int j = 0; j < 4; ++j) {      // output col-tile
        #pragma unroll
        for (int kk = 0; kk < 2; ++kk) {
            bf16x8 vh = *(const bf16x8*)&VtH[lr + 16 * j][kk * 32 + lg * 8];
            bf16x8 vl = *(const bf16x8*)&VtL[lr + 16 * j][kk * 32 + lg * 8];
            oacc[j] = mfma16(pfh[kk], vh, oacc[j]);
            oacc[j] = mfma16(pfl[kk], vh, oacc[j]);
            oacc[j] = mfma16(pfh[kk], vl, oacc[j]);
        }
    }

    // ---- epilogue: add off-block correction em/Z * vtot, store ----
    float vtd[4];
    #pragma unroll
    for (int j = 0; j < 4; ++j) vtd[j] = vt_lds[lr + 16 * j];

    float* op = O + base + (size_t)(w * 16) * D_;
    #pragma unroll
    for (int r = 0; r < 4; ++r) {
        float c = em[r] * inv[r];
        int row = lg * 4 + r;
        #pragma unroll
        for (int j = 0; j < 4; ++j) {
            int col = lr + 16 * j;
            op[row * D_ + col] = oacc[j][r] + c * vtd[j];
        }
    }
}

extern "C" void kernel_launch(void* const* d_in, const int* in_sizes, int n_in,
                              void* d_out, int out_size, void* d_ws, size_t ws_size,
                              hipStream_t stream) {
    const float* Q = (const float*)d_in[0];
    const float* K = (const float*)d_in[1];
    const float* V = (const float*)d_in[2];
    float* out = (float*)d_out;
    float* part = (float*)d_ws;   // H_*NSLICE*D_ floats = 128 KB

    vsum_part<<<H_ * NSLICE, 256, 0, stream>>>(V, part);
    battn<<<NUNITS, 256, 0, stream>>>(Q, K, V, part, out);
}

// Round 7
// 100.278 us; speedup vs baseline: 1.1441x; 1.0074x over previous
//
#include <hip/hip_runtime.h>

#define H_ 16
#define S_ 4096
#define D_ 64
#define NB_ 64            // S_/64
#define NUNITS (H_*NB_)   // 1024
#define NSLICE 32
#define ROWS_PER_SLICE (S_/NSLICE)  // 128

typedef __bf16 bf16x8 __attribute__((ext_vector_type(8)));
typedef float f32x4 __attribute__((ext_vector_type(4)));

static __device__ __forceinline__ f32x4 mfma16(bf16x8 a, bf16x8 b, f32x4 c) {
    return __builtin_amdgcn_mfma_f32_16x16x32_bf16(a, b, c, 0, 0, 0);
}

#define SPLIT1(x, hv, lv, idx) { float _x = (x); __bf16 _h = (__bf16)_x; (hv)[idx] = _h; (lv)[idx] = (__bf16)(_x - (float)_h); }

static __device__ __forceinline__ void split8(float4 a, float4 b, bf16x8& hi, bf16x8& lo) {
    SPLIT1(a.x, hi, lo, 0) SPLIT1(a.y, hi, lo, 1) SPLIT1(a.z, hi, lo, 2) SPLIT1(a.w, hi, lo, 3)
    SPLIT1(b.x, hi, lo, 4) SPLIT1(b.y, hi, lo, 5) SPLIT1(b.z, hi, lo, 6) SPLIT1(b.w, hi, lo, 7)
}

// ---------------- V partial row-sums: part[h][sl][d] = sum over 128 rows ----------------
__global__ __launch_bounds__(256) void vsum_part(const float* __restrict__ V,
                                                 float* __restrict__ part) {
    const int blk = blockIdx.x;            // h*NSLICE + slice
    const int h = blk >> 5, sl = blk & 31;
    const int t = threadIdx.x;
    const int d4 = t & 15, rg = t >> 4;
    const float4* vp = (const float4*)(V + ((size_t)h * S_ + (size_t)sl * ROWS_PER_SLICE) * D_);
    float4 acc = make_float4(0.f, 0.f, 0.f, 0.f);
    #pragma unroll
    for (int s = 0; s < ROWS_PER_SLICE / 16; ++s) {
        float4 v = vp[(rg + s * 16) * 16 + d4];
        acc.x += v.x; acc.y += v.y; acc.z += v.z; acc.w += v.w;
    }
    __shared__ float4 red[16][16];
    red[rg][d4] = acc;
    __syncthreads();
    if (rg == 0) {
        float4 s0 = red[0][d4];
        #pragma unroll
        for (int r = 1; r < 16; ++r) {
            float4 v = red[r][d4];
            s0.x += v.x; s0.y += v.y; s0.z += v.z; s0.w += v.w;
        }
        ((float4*)(part + (size_t)blk * D_))[d4] = s0;
    }
}

// ---------------- block attention: MFMA bf16 hi/lo split; XOR-swizzled Vt ----------------
// Vt LDS layout: element (n,k) lives at n*72 + (k ^ (((n>>2)&7)<<3)).
// 16-B-block XOR keeps b128 fragment reads aligned+ordered while spreading the
// strided transpose WRITES (4-row stride) from 2 banks to ~8 banks (16-way -> ~4-way).
__global__ __launch_bounds__(256, 4) void battn(const float* __restrict__ Q,
                                                const float* __restrict__ K,
                                                const float* __restrict__ V,
                                                const float* __restrict__ part,
                                                float* __restrict__ O) {
    const int unit = blockIdx.x;
    const int h = unit >> 6, b = unit & 63;
    const int t = threadIdx.x;
    const int w = t >> 6;          // wave 0..3, owns rows [w*16, w*16+16)
    const int lane = t & 63;
    const int lr = lane & 15;      // row/col within 16-tile
    const int lg = lane >> 4;      // k-group 0..3

    __shared__ __bf16 VtH[64 * 72];
    __shared__ __bf16 VtL[64 * 72];
    __shared__ __bf16 PH[64][72];
    __shared__ __bf16 PL[64][72];
    __shared__ float vt_lds[64];

    const size_t base = ((size_t)h * S_ + (size_t)b * 64) * D_;

    // ---- wave 0: reduce per-head V partials into vt_lds (visible after the barrier) ----
    if (t < 64) {
        const float* ph = part + (size_t)h * NSLICE * D_;
        float s = 0.f;
        #pragma unroll
        for (int sl = 0; sl < NSLICE; ++sl) s += ph[sl * D_ + t];
        vt_lds[t] = s;
    }

    // ---- stage V transposed as bf16 hi/lo, swizzled (coalesced float4 reads) ----
    const float4* v4 = (const float4*)(V + base);
    #pragma unroll
    for (int it = 0; it < 4; ++it) {
        int idx = t + it * 256;        // 0..1023
        int k  = idx >> 4;             // V row (seq pos in block)
        int n0 = (idx & 15) << 2;      // V col base (4 consecutive output rows)
        int kx = k ^ ((idx & 7) << 3); // swizzled k: (n>>2)&7 == idx&7 for all 4 rows
        float4 vv = v4[idx];
        { float x = vv.x; __bf16 hh = (__bf16)x; VtH[(n0+0)*72 + kx] = hh; VtL[(n0+0)*72 + kx] = (__bf16)(x - (float)hh); }
        { float x = vv.y; __bf16 hh = (__bf16)x; VtH[(n0+1)*72 + kx] = hh; VtL[(n0+1)*72 + kx] = (__bf16)(x - (float)hh); }
        { float x = vv.z; __bf16 hh = (__bf16)x; VtH[(n0+2)*72 + kx] = hh; VtL[(n0+2)*72 + kx] = (__bf16)(x - (float)hh); }
        { float x = vv.w; __bf16 hh = (__bf16)x; VtH[(n0+3)*72 + kx] = hh; VtL[(n0+3)*72 + kx] = (__bf16)(x - (float)hh); }
    }

    // ---- Q fragments (pre-scaled by 1/8; exact pow2, no extra rounding) ----
    bf16x8 qh[2], ql[2];
    {
        const float* qrow = Q + base + (size_t)(w * 16 + lr) * D_;
        #pragma unroll
        for (int kk = 0; kk < 2; ++kk) {
            const float4* p = (const float4*)(qrow + kk * 32 + lg * 8);
            float4 a = p[0], c2 = p[1];
            a.x *= 0.125f; a.y *= 0.125f; a.z *= 0.125f; a.w *= 0.125f;
            c2.x *= 0.125f; c2.y *= 0.125f; c2.z *= 0.125f; c2.w *= 0.125f;
            split8(a, c2, qh[kk], ql[kk]);
        }
    }

    // ---- S = (Q/8) K^T via 3-term split MFMA ----
    f32x4 acc[4];
    #pragma unroll
    for (int j = 0; j < 4; ++j) acc[j] = f32x4{0.f, 0.f, 0.f, 0.f};

    #pragma unroll
    for (int j = 0; j < 4; ++j) {      // K col-tile
        const float* krow = K + base + (size_t)(j * 16 + lr) * D_;
        #pragma unroll
        for (int kk = 0; kk < 2; ++kk) {
            const float4* p = (const float4*)(krow + kk * 32 + lg * 8);
            bf16x8 kh, kl;
            split8(p[0], p[1], kh, kl);
            acc[j] = mfma16(qh[kk], kh, acc[j]);
            acc[j] = mfma16(ql[kk], kh, acc[j]);
            acc[j] = mfma16(qh[kk], kl, acc[j]);
        }
    }

    // ---- softmax (row = w*16 + lg*4 + r, cols spread over 16 lanes x 4 tiles) ----
    float em[4], inv[4];
    #pragma unroll
    for (int r = 0; r < 4; ++r) {
        float mx = fmaxf(fmaxf(acc[0][r], acc[1][r]), fmaxf(acc[2][r], acc[3][r]));
        #pragma unroll
        for (int off = 1; off < 16; off <<= 1) mx = fmaxf(mx, __shfl_xor(mx, off, 16));
        mx = fmaxf(mx, 0.f);           // off-block entries have score 0
        float e = __expf(-mx);
        float p0 = __expf(acc[0][r] - mx) - e;
        float p1 = __expf(acc[1][r] - mx) - e;
        float p2 = __expf(acc[2][r] - mx) - e;
        float p3 = __expf(acc[3][r] - mx) - e;
        float zs = p0 + p1 + p2 + p3;
        #pragma unroll
        for (int off = 1; off < 16; off <<= 1) zs += __shfl_xor(zs, off, 16);
        float iv = 1.0f / (zs + 4096.0f * e);   // Z = sum_p + S*e^{-m}
        em[r] = e; inv[r] = iv;
        int row = w * 16 + lg * 4 + r;
        { float pn = p0 * iv; __bf16 hh = (__bf16)pn; PH[row][lr +  0] = hh; PL[row][lr +  0] = (__bf16)(pn - (float)hh); }
        { float pn = p1 * iv; __bf16 hh = (__bf16)pn; PH[row][lr + 16] = hh; PL[row][lr + 16] = (__bf16)(pn - (float)hh); }
        { float pn = p2 * iv; __bf16 hh = (__bf16)pn; PH[row][lr + 32] = hh; PL[row][lr + 32] = (__bf16)(pn - (float)hh); }
        { float pn = p3 * iv; __bf16 hh = (__bf16)pn; PH[row][lr + 48] = hh; PL[row][lr + 48] = (__bf16)(pn - (float)hh); }
    }

    __syncthreads();   // V staging + vt_lds visibility across waves (P is intra-wave only)

    // ---- O = P V via 3-term split MFMA ----
    bf16x8 pfh[2], pfl[2];
    {
        const int prow = w * 16 + lr;
        #pragma unroll
        for (int kk = 0; kk < 2; ++kk) {
            pfh[kk] = *(const bf16x8*)&PH[prow][kk * 32 + lg * 8];
            pfl[kk] = *(const bf16x8*)&PL[prow][kk * 32 + lg * 8];
        }
    }

    f32x4 oacc[4];
    #pragma unroll
    for (int j = 0; j < 4; ++j) oacc[j] = f32x4{0.f, 0.f, 0.f, 0.f};

    #pragma unroll
    for (int j = 0; j < 4; ++j) {      // output col-tile
        const int n = lr + 16 * j;
        const int sw = ((n >> 2) & 7) << 3;
        #pragma unroll
        for (int kk = 0; kk < 2; ++kk) {
            int k0 = (kk * 32 + lg * 8) ^ sw;
            bf16x8 vh = *(const bf16x8*)&VtH[n * 72 + k0];
            bf16x8 vl = *(const bf16x8*)&VtL[n * 72 + k0];
            oacc[j] = mfma16(pfh[kk], vh, oacc[j]);
            oacc[j] = mfma16(pfl[kk], vh, oacc[j]);
            oacc[j] = mfma16(pfh[kk], vl, oacc[j]);
        }
    }

    // ---- epilogue: add off-block correction em/Z * vtot, store ----
    float vtd[4];
    #pragma unroll
    for (int j = 0; j < 4; ++j) vtd[j] = vt_lds[lr + 16 * j];

    float* op = O + base + (size_t)(w * 16) * D_;
    #pragma unroll
    for (int r = 0; r < 4; ++r) {
        float c = em[r] * inv[r];
        int row = lg * 4 + r;
        #pragma unroll
        for (int j = 0; j < 4; ++j) {
            int col = lr + 16 * j;
            op[row * D_ + col] = oacc[j][r] + c * vtd[j];
        }
    }
}

extern "C" void kernel_launch(void* const* d_in, const int* in_sizes, int n_in,
                              void* d_out, int out_size, void* d_ws, size_t ws_size,
                              hipStream_t stream) {
    const float* Q = (const float*)d_in[0];
    const float* K = (const float*)d_in[1];
    const float* V = (const float*)d_in[2];
    float* out = (float*)d_out;
    float* part = (float*)d_ws;   // H_*NSLICE*D_ floats = 128 KB

    vsum_part<<<H_ * NSLICE, 256, 0, stream>>>(V, part);
    battn<<<NUNITS, 256, 0, stream>>>(Q, K, V, part, out);
}